// Round 1
// baseline (1051.738 us; speedup 1.0000x reference)
//
#include <hip/hip_runtime.h>

#define NN 50000
#define NE 1600000
#define DIM 128
#define NG  512

__device__ __forceinline__ float bcast_lane(float v, int lane) {
    return __int_as_float(__builtin_amdgcn_readlane(__float_as_int(v), lane));
}

// ---------------- init: zero cnt + pooled ----------------
__global__ void init_kernel(int* __restrict__ cnt, float* __restrict__ pooled) {
    int i = blockIdx.x * blockDim.x + threadIdx.x;
    int stride = gridDim.x * blockDim.x;
    for (int j = i; j < NN; j += stride) cnt[j] = 0;
    for (int j = i; j < NG * DIM; j += stride) pooled[j] = 0.f;
}

// ---------------- in-degree count (by dst) ----------------
__global__ void count_kernel(const int* __restrict__ dst, int* __restrict__ cnt) {
    int e = blockIdx.x * blockDim.x + threadIdx.x;
    if (e < NE) atomicAdd(&cnt[dst[e]], 1);
}

// ---------------- exclusive scan (single block) + coeffs ----------------
__global__ void scan_kernel(const int* __restrict__ cnt, int* __restrict__ rowp,
                            int* __restrict__ cursor, float* __restrict__ disqrt,
                            float* __restrict__ selfn) {
    __shared__ int sdata[1024];
    __shared__ int s_carry;
    int t = threadIdx.x;
    if (t == 0) s_carry = 0;
    __syncthreads();
    for (int base = 0; base < NN; base += 1024) {
        int i = base + t;
        int v = (i < NN) ? cnt[i] : 0;
        sdata[t] = v;
        __syncthreads();
        for (int off = 1; off < 1024; off <<= 1) {
            int add = (t >= off) ? sdata[t - off] : 0;
            __syncthreads();
            sdata[t] += add;
            __syncthreads();
        }
        int incl = sdata[t];
        int excl = incl - v;
        int carry = s_carry;
        if (i < NN) {
            rowp[i] = carry + excl;
            cursor[i] = carry + excl;
            float dg = (float)(v + 1);          // degree with self-loop
            disqrt[i] = 1.0f / sqrtf(dg);
            selfn[i] = 1.0f / dg;
        }
        __syncthreads();
        if (t == 1023) s_carry = carry + incl;  // incl at t=1023 == tile total
        __syncthreads();
    }
    if (t == 0) rowp[NN] = s_carry;
}

// ---------------- scatter edges into CSR (sorted by dst) ----------------
__global__ void scatter_kernel(const int* __restrict__ src, const int* __restrict__ dst,
                               const float* __restrict__ disqrt, int* __restrict__ cursor,
                               int* __restrict__ ssrc, float* __restrict__ snorm) {
    int e = blockIdx.x * blockDim.x + threadIdx.x;
    if (e >= NE) return;
    int s = src[e], d = dst[e];
    float en = disqrt[s] * disqrt[d];
    int pos = atomicAdd(&cursor[d], 1);
    ssrc[pos] = s;
    snorm[pos] = en;
}

// ---------------- GEMM: out[N,128] = xin[N,128] @ W[128,128] ----------------
// W staged in LDS (64 KB). 4 rows per 256-thread block iter (1 wave/row).
// x-row broadcast via readlane; W read as float2 (ds_read_b64).
__launch_bounds__(256, 2)
__global__ void gemm_kernel(const float* __restrict__ xin, const float* __restrict__ W,
                            float* __restrict__ out) {
    __shared__ float sW[DIM * DIM];   // 64 KB
    for (int i = threadIdx.x; i < DIM * DIM; i += 256) sW[i] = W[i];
    __syncthreads();
    const float2* sW2 = (const float2*)sW;
    int wid = threadIdx.x >> 6;       // wave id 0..3 -> row within quad
    int lane = threadIdx.x & 63;
    for (int base = blockIdx.x * 4; base < NN; base += gridDim.x * 4) {
        int row = base + wid;         // NN % 4 == 0, always valid
        const float* xr = xin + row * DIM;
        float xa = xr[lane];
        float xb = xr[lane + 64];
        float ax = 0.f, ay = 0.f;
#pragma unroll
        for (int j = 0; j < 64; ++j) {
            float xj = bcast_lane(xa, j);
            float2 w2 = sW2[j * 64 + lane];
            ax += xj * w2.x;
            ay += xj * w2.y;
        }
#pragma unroll
        for (int j = 0; j < 64; ++j) {
            float xj = bcast_lane(xb, j);
            float2 w2 = sW2[(j + 64) * 64 + lane];
            ax += xj * w2.x;
            ay += xj * w2.y;
        }
        float2* o2 = (float2*)(out + row * DIM);
        o2[lane] = make_float2(ax, ay);
    }
}

// ---------------- fused conv: aggregate + self + bias + L2norm + ReLU (+pool) ----------------
// One wave per node; thread lane covers cols 2*lane, 2*lane+1 (float2).
__launch_bounds__(256, 4)
__global__ void conv_kernel(const float* __restrict__ h, const float* __restrict__ bias,
                            const int* __restrict__ rowp, const int* __restrict__ ssrc,
                            const float* __restrict__ snorm, const float* __restrict__ selfn,
                            float* __restrict__ out, const int* __restrict__ batch,
                            float* __restrict__ pooled, int do_pool) {
    int wid = threadIdx.x >> 6;
    int lane = threadIdx.x & 63;
    int node = blockIdx.x * 4 + wid;
    if (node >= NN) return;
    int beg = rowp[node], end = rowp[node + 1];
    const float2* h2 = (const float2*)h;
    float ax = 0.f, ay = 0.f;
#pragma unroll 2
    for (int e = beg; e < end; ++e) {
        int s = ssrc[e];
        float wgt = snorm[e];
        float2 v = h2[s * 64 + lane];
        ax += wgt * v.x;
        ay += wgt * v.y;
    }
    float sn = selfn[node];
    float2 hv = h2[node * 64 + lane];
    ax += sn * hv.x + bias[2 * lane];
    ay += sn * hv.y + bias[2 * lane + 1];
    // row L2 norm across the wave
    float ss = ax * ax + ay * ay;
#pragma unroll
    for (int off = 32; off; off >>= 1) ss += __shfl_xor(ss, off);
    float inv = 1.0f / fmaxf(sqrtf(ss), 1e-12f);
    float ox = fmaxf(ax * inv, 0.f);
    float oy = fmaxf(ay * inv, 0.f);
    float2* o2 = (float2*)out;
    o2[node * 64 + lane] = make_float2(ox, oy);
    if (do_pool) {
        int g = batch[node];
        atomicAdd(&pooled[g * DIM + 2 * lane], ox);
        atomicAdd(&pooled[g * DIM + 2 * lane + 1], oy);
    }
}

// ---------------- head: z = relu(pooled@W1+b1); logits = z@W2+b2 ----------------
__launch_bounds__(128)
__global__ void head_kernel(const float* __restrict__ pooled, const float* __restrict__ w1,
                            const float* __restrict__ b1, const float* __restrict__ w2,
                            const float* __restrict__ b2, float* __restrict__ out) {
    __shared__ float sp[DIM];
    __shared__ float red[4];
    int g = blockIdx.x;
    int k = threadIdx.x;
    sp[k] = pooled[g * DIM + k];
    __syncthreads();
    float acc = b1[k];
#pragma unroll 8
    for (int j = 0; j < DIM; ++j) acc += sp[j] * w1[j * DIM + k];
    float z = fmaxf(acc, 0.f);
    float p0 = z * w2[k * 2 + 0];
    float p1 = z * w2[k * 2 + 1];
#pragma unroll
    for (int off = 32; off; off >>= 1) {
        p0 += __shfl_xor(p0, off);
        p1 += __shfl_xor(p1, off);
    }
    if ((k & 63) == 0) {
        red[(k >> 6) * 2 + 0] = p0;
        red[(k >> 6) * 2 + 1] = p1;
    }
    __syncthreads();
    if (k == 0) {
        out[g * 2 + 0] = red[0] + red[2] + b2[0];
        out[g * 2 + 1] = red[1] + red[3] + b2[1];
    }
}

extern "C" void kernel_launch(void* const* d_in, const int* in_sizes, int n_in,
                              void* d_out, int out_size, void* d_ws, size_t ws_size,
                              hipStream_t stream) {
    const float* x    = (const float*)d_in[0];
    const int* eidx   = (const int*)d_in[1];
    const int* batch  = (const int*)d_in[2];
    const float* W0   = (const float*)d_in[3];
    const float* b0   = (const float*)d_in[4];
    const float* W1   = (const float*)d_in[5];
    const float* b1   = (const float*)d_in[6];
    const float* W2   = (const float*)d_in[7];
    const float* b2   = (const float*)d_in[8];
    const float* l1w  = (const float*)d_in[9];
    const float* l1b  = (const float*)d_in[10];
    const float* l2w  = (const float*)d_in[11];
    const float* l2b  = (const float*)d_in[12];
    float* out = (float*)d_out;

    char* w = (char*)d_ws;
    float* disqrt = (float*)w; w += (size_t)NN * 4;
    float* selfn  = (float*)w; w += (size_t)NN * 4;
    int*   cnt    = (int*)w;   w += (size_t)NN * 4;
    int*   rowp   = (int*)w;   w += (size_t)(NN + 8) * 4;
    int*   cursor = (int*)w;   w += (size_t)NN * 4;
    int*   ssrc   = (int*)w;   w += (size_t)NE * 4;
    float* snorm  = (float*)w; w += (size_t)NE * 4;
    float* buf0   = (float*)w; w += (size_t)NN * DIM * 4;
    float* buf1   = (float*)w; w += (size_t)NN * DIM * 4;
    float* pooled = (float*)w; w += (size_t)NG * DIM * 4;

    const int* src = eidx;
    const int* dst = eidx + NE;

    init_kernel<<<256, 256, 0, stream>>>(cnt, pooled);
    count_kernel<<<(NE + 255) / 256, 256, 0, stream>>>(dst, cnt);
    scan_kernel<<<1, 1024, 0, stream>>>(cnt, rowp, cursor, disqrt, selfn);
    scatter_kernel<<<(NE + 255) / 256, 256, 0, stream>>>(src, dst, disqrt, cursor, ssrc, snorm);

    gemm_kernel<<<512, 256, 0, stream>>>(x, W0, buf0);
    conv_kernel<<<(NN + 3) / 4, 256, 0, stream>>>(buf0, b0, rowp, ssrc, snorm, selfn, buf1,
                                                  batch, pooled, 0);
    gemm_kernel<<<512, 256, 0, stream>>>(buf1, W1, buf0);
    conv_kernel<<<(NN + 3) / 4, 256, 0, stream>>>(buf0, b1, rowp, ssrc, snorm, selfn, buf1,
                                                  batch, pooled, 0);
    gemm_kernel<<<512, 256, 0, stream>>>(buf1, W2, buf0);
    conv_kernel<<<(NN + 3) / 4, 256, 0, stream>>>(buf0, b2, rowp, ssrc, snorm, selfn, buf1,
                                                  batch, pooled, 1);
    head_kernel<<<NG, 128, 0, stream>>>(pooled, l1w, l1b, l2w, l2b, out);
}

// Round 3
// 683.287 us; speedup vs baseline: 1.5392x; 1.5392x over previous
//
#include <hip/hip_runtime.h>

#define NN 50000
#define NE 1600000
#define DIM 128
#define NG  512
#define NBLK 196   // ceil(NN/256)

typedef int   vint2   __attribute__((ext_vector_type(2)));
typedef float vfloat2 __attribute__((ext_vector_type(2)));

__device__ __forceinline__ float bcast_lane(float v, int lane) {
    return __int_as_float(__builtin_amdgcn_readlane(__float_as_int(v), lane));
}
__device__ __forceinline__ float bf2f(unsigned short b) {
    return __uint_as_float(((unsigned int)b) << 16);
}
__device__ __forceinline__ unsigned short f2bf(float f) {
    unsigned int u = __float_as_uint(f);
    u += 0x7fffu + ((u >> 16) & 1u);   // round-to-nearest-even (finite inputs)
    return (unsigned short)(u >> 16);
}

// ---------------- init: zero cnt + pooled ----------------
__global__ void init_kernel(int* __restrict__ cnt, float* __restrict__ pooled) {
    int i = blockIdx.x * blockDim.x + threadIdx.x;
    int stride = gridDim.x * blockDim.x;
    for (int j = i; j < NN; j += stride) cnt[j] = 0;
    for (int j = i; j < NG * DIM; j += stride) pooled[j] = 0.f;
}

// ---------------- in-degree count (by dst) ----------------
__global__ void count_kernel(const int* __restrict__ dst, int* __restrict__ cnt) {
    int e = blockIdx.x * blockDim.x + threadIdx.x;
    if (e < NE) atomicAdd(&cnt[__builtin_nontemporal_load(dst + e)], 1);
}

// ---------------- scan phase 1: per-block local scan + coeffs ----------------
__global__ void scan1_kernel(const int* __restrict__ cnt, int* __restrict__ lexcl,
                             int* __restrict__ bsum, float* __restrict__ disqrt,
                             float* __restrict__ selfn) {
    __shared__ int sd[256];
    int t = threadIdx.x;
    int i = blockIdx.x * 256 + t;
    int v = (i < NN) ? cnt[i] : 0;
    sd[t] = v;
    __syncthreads();
    for (int off = 1; off < 256; off <<= 1) {
        int add = (t >= off) ? sd[t - off] : 0;
        __syncthreads();
        sd[t] += add;
        __syncthreads();
    }
    int incl = sd[t];
    if (i < NN) {
        lexcl[i] = incl - v;
        float dg = (float)(v + 1);
        disqrt[i] = 1.0f / sqrtf(dg);
        selfn[i] = 1.0f / dg;
    }
    if (t == 255) bsum[blockIdx.x] = incl;
}

// ---------------- scan phase 2: scan block sums (single block) ----------------
__global__ void scan2_kernel(const int* __restrict__ bsum, int* __restrict__ boffs,
                             int* __restrict__ rowp) {
    __shared__ int sd[256];
    int t = threadIdx.x;
    int v = (t < NBLK) ? bsum[t] : 0;
    sd[t] = v;
    __syncthreads();
    for (int off = 1; off < 256; off <<= 1) {
        int add = (t >= off) ? sd[t - off] : 0;
        __syncthreads();
        sd[t] += add;
        __syncthreads();
    }
    int incl = sd[t];
    if (t < NBLK) boffs[t] = incl - v;
    if (t == 255) rowp[NN] = incl;   // grand total (== NE)
}

// ---------------- scan phase 3: global offsets ----------------
__global__ void scan3_kernel(const int* __restrict__ lexcl, const int* __restrict__ boffs,
                             int* __restrict__ rowp, int* __restrict__ cursor) {
    int i = blockIdx.x * 256 + threadIdx.x;
    if (i < NN) {
        int v = lexcl[i] + boffs[blockIdx.x];
        rowp[i] = v;
        cursor[i] = v;
    }
}

// ---------------- scatter edges into CSR (packed {src, norm} as vint2) ----------------
__global__ void scatter_kernel(const int* __restrict__ src, const int* __restrict__ dst,
                               const float* __restrict__ disqrt, int* __restrict__ cursor,
                               vint2* __restrict__ edges) {
    int e = blockIdx.x * blockDim.x + threadIdx.x;
    if (e >= NE) return;
    int s = __builtin_nontemporal_load(src + e);
    int d = __builtin_nontemporal_load(dst + e);
    float en = disqrt[s] * disqrt[d];
    int pos = atomicAdd(&cursor[d], 1);
    vint2 rec;
    rec.x = s;
    rec.y = __float_as_int(en);
    __builtin_nontemporal_store(rec, edges + pos);
}

// ---------------- GEMM: h[N,128](bf16) = y[N,128](fp32) @ W[128,128] ----------------
// W in LDS (64 KB). 4 waves/block, 4 rows per wave: one ds_read_b64 feeds 8 FMAs.
__launch_bounds__(256, 2)
__global__ void gemm_kernel(const float* __restrict__ xin, const float* __restrict__ W,
                            ushort2* __restrict__ outh) {
    __shared__ float sW[DIM * DIM];   // 64 KB
    for (int i = threadIdx.x; i < DIM * DIM; i += 256) sW[i] = W[i];
    __syncthreads();
    const float2* sW2 = (const float2*)sW;
    int wid = threadIdx.x >> 6;
    int lane = threadIdx.x & 63;
    for (int base = blockIdx.x * 16; base < NN; base += gridDim.x * 16) {
        int r0 = base + wid * 4;      // NN % 16 == 0, always valid
        float xa[4], xb[4], ax[4], ay[4];
#pragma unroll
        for (int r = 0; r < 4; ++r) {
            const float* xr = xin + (size_t)(r0 + r) * DIM;
            xa[r] = __builtin_nontemporal_load(xr + lane);
            xb[r] = __builtin_nontemporal_load(xr + 64 + lane);
            ax[r] = 0.f; ay[r] = 0.f;
        }
#pragma unroll 4
        for (int j = 0; j < 64; ++j) {
            float2 w2 = sW2[j * 64 + lane];
#pragma unroll
            for (int r = 0; r < 4; ++r) {
                float t = bcast_lane(xa[r], j);
                ax[r] += t * w2.x;
                ay[r] += t * w2.y;
            }
        }
#pragma unroll 4
        for (int j = 0; j < 64; ++j) {
            float2 w2 = sW2[(j + 64) * 64 + lane];
#pragma unroll
            for (int r = 0; r < 4; ++r) {
                float t = bcast_lane(xb[r], j);
                ax[r] += t * w2.x;
                ay[r] += t * w2.y;
            }
        }
#pragma unroll
        for (int r = 0; r < 4; ++r) {
            unsigned int packed = ((unsigned int)f2bf(ay[r]) << 16) | f2bf(ax[r]);
            __builtin_nontemporal_store(packed, (unsigned int*)(outh + (size_t)(r0 + r) * 64 + lane));
        }
    }
}

// ---------------- fused conv: agg(bf16 gather) + self + bias + L2norm + ReLU (+pool) ----
__launch_bounds__(256, 4)
__global__ void conv_kernel(const ushort2* __restrict__ h2, const float* __restrict__ bias,
                            const int* __restrict__ rowp, const vint2* __restrict__ edges,
                            const float* __restrict__ selfn, float* __restrict__ out,
                            const int* __restrict__ batch, float* __restrict__ pooled,
                            int do_pool) {
    int wid = threadIdx.x >> 6;
    int lane = threadIdx.x & 63;
    int node = blockIdx.x * 4 + wid;
    if (node >= NN) return;
    int beg = rowp[node], end = rowp[node + 1];
    float ax = 0.f, ay = 0.f;
    int e = beg;
    for (; e + 4 <= end; e += 4) {
        vint2 r0 = __builtin_nontemporal_load(edges + e);
        vint2 r1 = __builtin_nontemporal_load(edges + e + 1);
        vint2 r2 = __builtin_nontemporal_load(edges + e + 2);
        vint2 r3 = __builtin_nontemporal_load(edges + e + 3);
        ushort2 v0 = h2[(size_t)r0.x * 64 + lane];
        ushort2 v1 = h2[(size_t)r1.x * 64 + lane];
        ushort2 v2 = h2[(size_t)r2.x * 64 + lane];
        ushort2 v3 = h2[(size_t)r3.x * 64 + lane];
        float w0 = __int_as_float(r0.y), w1 = __int_as_float(r1.y);
        float w2 = __int_as_float(r2.y), w3 = __int_as_float(r3.y);
        ax += w0 * bf2f(v0.x) + w1 * bf2f(v1.x) + w2 * bf2f(v2.x) + w3 * bf2f(v3.x);
        ay += w0 * bf2f(v0.y) + w1 * bf2f(v1.y) + w2 * bf2f(v2.y) + w3 * bf2f(v3.y);
    }
    for (; e < end; ++e) {
        vint2 r = __builtin_nontemporal_load(edges + e);
        ushort2 v = h2[(size_t)r.x * 64 + lane];
        float w = __int_as_float(r.y);
        ax += w * bf2f(v.x);
        ay += w * bf2f(v.y);
    }
    float sn = selfn[node];
    ushort2 hv = h2[(size_t)node * 64 + lane];
    ax += sn * bf2f(hv.x) + bias[2 * lane];
    ay += sn * bf2f(hv.y) + bias[2 * lane + 1];
    float ss = ax * ax + ay * ay;
#pragma unroll
    for (int off = 32; off; off >>= 1) ss += __shfl_xor(ss, off);
    float inv = 1.0f / fmaxf(sqrtf(ss), 1e-12f);
    float ox = fmaxf(ax * inv, 0.f);
    float oy = fmaxf(ay * inv, 0.f);
    vfloat2 o;
    o.x = ox; o.y = oy;
    __builtin_nontemporal_store(o, (vfloat2*)out + (size_t)node * 64 + lane);
    if (do_pool) {
        int g = batch[node];
        atomicAdd(&pooled[g * DIM + 2 * lane], ox);
        atomicAdd(&pooled[g * DIM + 2 * lane + 1], oy);
    }
}

// ---------------- head: z = relu(pooled@W1+b1); logits = z@W2+b2 ----------------
__launch_bounds__(128)
__global__ void head_kernel(const float* __restrict__ pooled, const float* __restrict__ w1,
                            const float* __restrict__ b1, const float* __restrict__ w2,
                            const float* __restrict__ b2, float* __restrict__ out) {
    __shared__ float sp[DIM];
    __shared__ float red[4];
    int g = blockIdx.x;
    int k = threadIdx.x;
    sp[k] = pooled[g * DIM + k];
    __syncthreads();
    float acc = b1[k];
#pragma unroll 8
    for (int j = 0; j < DIM; ++j) acc += sp[j] * w1[j * DIM + k];
    float z = fmaxf(acc, 0.f);
    float p0 = z * w2[k * 2 + 0];
    float p1 = z * w2[k * 2 + 1];
#pragma unroll
    for (int off = 32; off; off >>= 1) {
        p0 += __shfl_xor(p0, off);
        p1 += __shfl_xor(p1, off);
    }
    if ((k & 63) == 0) {
        red[(k >> 6) * 2 + 0] = p0;
        red[(k >> 6) * 2 + 1] = p1;
    }
    __syncthreads();
    if (k == 0) {
        out[g * 2 + 0] = red[0] + red[2] + b2[0];
        out[g * 2 + 1] = red[1] + red[3] + b2[1];
    }
}

extern "C" void kernel_launch(void* const* d_in, const int* in_sizes, int n_in,
                              void* d_out, int out_size, void* d_ws, size_t ws_size,
                              hipStream_t stream) {
    const float* x    = (const float*)d_in[0];
    const int* eidx   = (const int*)d_in[1];
    const int* batch  = (const int*)d_in[2];
    const float* W0   = (const float*)d_in[3];
    const float* b0   = (const float*)d_in[4];
    const float* W1   = (const float*)d_in[5];
    const float* b1   = (const float*)d_in[6];
    const float* W2   = (const float*)d_in[7];
    const float* b2   = (const float*)d_in[8];
    const float* l1w  = (const float*)d_in[9];
    const float* l1b  = (const float*)d_in[10];
    const float* l2w  = (const float*)d_in[11];
    const float* l2b  = (const float*)d_in[12];
    float* out = (float*)d_out;

    char* w = (char*)d_ws;
    float* disqrt = (float*)w; w += (size_t)NN * 4;
    float* selfn  = (float*)w; w += (size_t)NN * 4;
    int*   cnt    = (int*)w;   w += (size_t)NN * 4;
    int*   rowp   = (int*)w;   w += (size_t)(NN + 8) * 4;
    int*   cursor = (int*)w;   w += (size_t)NN * 4;
    int*   lexcl  = (int*)w;   w += (size_t)NN * 4;
    int*   bsum   = (int*)w;   w += 256 * 4;
    int*   boffs  = (int*)w;   w += 256 * 4;
    vint2* edges  = (vint2*)w; w += (size_t)NE * 8;
    ushort2* bufh = (ushort2*)w; w += (size_t)NN * DIM * 2;   // bf16 h
    float* bufy   = (float*)w; w += (size_t)NN * DIM * 4;     // fp32 y
    float* pooled = (float*)w; w += (size_t)NG * DIM * 4;

    const int* src = eidx;
    const int* dst = eidx + NE;

    init_kernel<<<256, 256, 0, stream>>>(cnt, pooled);
    count_kernel<<<(NE + 255) / 256, 256, 0, stream>>>(dst, cnt);
    scan1_kernel<<<NBLK, 256, 0, stream>>>(cnt, lexcl, bsum, disqrt, selfn);
    scan2_kernel<<<1, 256, 0, stream>>>(bsum, boffs, rowp);
    scan3_kernel<<<NBLK, 256, 0, stream>>>(lexcl, boffs, rowp, cursor);
    scatter_kernel<<<(NE + 255) / 256, 256, 0, stream>>>(src, dst, disqrt, cursor, edges);

    gemm_kernel<<<512, 256, 0, stream>>>(x, W0, bufh);
    conv_kernel<<<(NN + 3) / 4, 256, 0, stream>>>(bufh, b0, rowp, edges, selfn, bufy,
                                                  batch, pooled, 0);
    gemm_kernel<<<512, 256, 0, stream>>>(bufy, W1, bufh);
    conv_kernel<<<(NN + 3) / 4, 256, 0, stream>>>(bufh, b1, rowp, edges, selfn, bufy,
                                                  batch, pooled, 0);
    gemm_kernel<<<512, 256, 0, stream>>>(bufy, W2, bufh);
    conv_kernel<<<(NN + 3) / 4, 256, 0, stream>>>(bufh, b2, rowp, edges, selfn, bufy,
                                                  batch, pooled, 1);
    head_kernel<<<NG, 128, 0, stream>>>(pooled, l1w, l1b, l2w, l2b, out);
}

// Round 4
// 582.844 us; speedup vs baseline: 1.8045x; 1.1723x over previous
//
#include <hip/hip_runtime.h>

#define NN 50000
#define NE 1600000
#define DIM 128
#define NG  512
#define NBLK 196   // ceil(NN/256)

typedef int      vint2   __attribute__((ext_vector_type(2)));
typedef float    vfloat4 __attribute__((ext_vector_type(4)));
typedef float    floatx4 __attribute__((ext_vector_type(4)));
typedef _Float16 half2v  __attribute__((ext_vector_type(2)));
typedef _Float16 half4v  __attribute__((ext_vector_type(4)));
typedef _Float16 half8   __attribute__((ext_vector_type(8)));

// ---------------- init: zero cnt + pooled ----------------
__global__ void init_kernel(int* __restrict__ cnt, float* __restrict__ pooled) {
    int i = blockIdx.x * blockDim.x + threadIdx.x;
    int stride = gridDim.x * blockDim.x;
    for (int j = i; j < NN; j += stride) cnt[j] = 0;
    for (int j = i; j < NG * DIM; j += stride) pooled[j] = 0.f;
}

// ---------------- in-degree count (by dst) ----------------
__global__ void count_kernel(const int* __restrict__ dst, int* __restrict__ cnt) {
    int e = blockIdx.x * blockDim.x + threadIdx.x;
    if (e < NE) atomicAdd(&cnt[__builtin_nontemporal_load(dst + e)], 1);
}

// ---------------- scan phase 1: per-block local scan + coeffs ----------------
__global__ void scan1_kernel(const int* __restrict__ cnt, int* __restrict__ lexcl,
                             int* __restrict__ bsum, float* __restrict__ disqrt,
                             float* __restrict__ selfn) {
    __shared__ int sd[256];
    int t = threadIdx.x;
    int i = blockIdx.x * 256 + t;
    int v = (i < NN) ? cnt[i] : 0;
    sd[t] = v;
    __syncthreads();
    for (int off = 1; off < 256; off <<= 1) {
        int add = (t >= off) ? sd[t - off] : 0;
        __syncthreads();
        sd[t] += add;
        __syncthreads();
    }
    int incl = sd[t];
    if (i < NN) {
        lexcl[i] = incl - v;
        float dg = (float)(v + 1);
        disqrt[i] = 1.0f / sqrtf(dg);
        selfn[i] = 1.0f / dg;
    }
    if (t == 255) bsum[blockIdx.x] = incl;
}

// ---------------- scan phase 2: scan block sums (single block) ----------------
__global__ void scan2_kernel(const int* __restrict__ bsum, int* __restrict__ boffs,
                             int* __restrict__ rowp) {
    __shared__ int sd[256];
    int t = threadIdx.x;
    int v = (t < NBLK) ? bsum[t] : 0;
    sd[t] = v;
    __syncthreads();
    for (int off = 1; off < 256; off <<= 1) {
        int add = (t >= off) ? sd[t - off] : 0;
        __syncthreads();
        sd[t] += add;
        __syncthreads();
    }
    int incl = sd[t];
    if (t < NBLK) boffs[t] = incl - v;
    if (t == 255) rowp[NN] = incl;   // grand total (== NE)
}

// ---------------- scan phase 3: global offsets ----------------
__global__ void scan3_kernel(const int* __restrict__ lexcl, const int* __restrict__ boffs,
                             int* __restrict__ rowp, int* __restrict__ cursor) {
    int i = blockIdx.x * 256 + threadIdx.x;
    if (i < NN) {
        int v = lexcl[i] + boffs[blockIdx.x];
        rowp[i] = v;
        cursor[i] = v;
    }
}

// ---------------- scatter edges into CSR (packed {src, norm} as vint2) ----------------
__global__ void scatter_kernel(const int* __restrict__ src, const int* __restrict__ dst,
                               const float* __restrict__ disqrt, int* __restrict__ cursor,
                               vint2* __restrict__ edges) {
    int e = blockIdx.x * blockDim.x + threadIdx.x;
    if (e >= NE) return;
    int s = __builtin_nontemporal_load(src + e);
    int d = __builtin_nontemporal_load(dst + e);
    float en = disqrt[s] * disqrt[d];
    int pos = atomicAdd(&cursor[d], 1);
    vint2 rec;
    rec.x = s;
    rec.y = __float_as_int(en);
    __builtin_nontemporal_store(rec, edges + pos);
}

// ---------------- convert x fp32 -> fp16 ----------------
__global__ void cvt_kernel(const float* __restrict__ x, _Float16* __restrict__ xh) {
    int i = blockIdx.x * 256 + threadIdx.x;   // one float4 per thread
    if (i >= NN * DIM / 4) return;
    vfloat4 v = ((const vfloat4*)x)[i];
    half4v o;
    o.x = (_Float16)v.x; o.y = (_Float16)v.y;
    o.z = (_Float16)v.z; o.w = (_Float16)v.w;
    ((half4v*)xh)[i] = o;
}

// ---------------- GEMM via MFMA: h[N,128](fp16) = y[N,128](fp16) @ W[128,128](fp32->fp16) --
// A-frag (16x16x32 f16): A[m=lane&15][k=(lane>>4)*8+j]
// B-frag:                B[k=(lane>>4)*8+j][n=lane&15]
// C/D:                   C[row=(lane>>4)*4+r][col=lane&15]
__launch_bounds__(256, 2)
__global__ void gemm_mfma(const _Float16* __restrict__ yin, const float* __restrict__ W,
                          _Float16* __restrict__ hout) {
    __shared__ half8 Wf[2048];   // 4 ksteps x 8 ntiles x 64 lanes, 32 KB
    int tid = threadIdx.x;
    for (int idx = tid; idx < 2048; idx += 256) {
        int t = idx >> 9;
        int n = (idx >> 6) & 7;
        int ln = idx & 63;
        int q = ln >> 4, c = ln & 15;
        const float* wp = W + (t * 32 + q * 8) * DIM + n * 16 + c;
        half8 f;
#pragma unroll
        for (int j = 0; j < 8; ++j) f[j] = (_Float16)wp[j * DIM];
        Wf[idx] = f;
    }
    __syncthreads();
    int wid = tid >> 6, lane = tid & 63;
    int q = lane >> 4, m = lane & 15;
    const int ngroups = (NN + 63) / 64;   // 782
    for (int g = blockIdx.x; g < ngroups; g += gridDim.x) {
        int r0 = g * 64 + wid * 16;
        int arow = r0 + m;
        if (arow > NN - 1) arow = NN - 1;      // clamp; corrupt rows never stored
        const half8* ap = (const half8*)(yin + (size_t)arow * DIM + q * 8);
        half8 a0 = ap[0], a1 = ap[4], a2 = ap[8], a3 = ap[12];   // k += 32 per step
        floatx4 acc[8];
#pragma unroll
        for (int n = 0; n < 8; ++n) acc[n] = (floatx4){0.f, 0.f, 0.f, 0.f};
#pragma unroll
        for (int n = 0; n < 8; ++n)
            acc[n] = __builtin_amdgcn_mfma_f32_16x16x32_f16(a0, Wf[(0 * 8 + n) * 64 + lane], acc[n], 0, 0, 0);
#pragma unroll
        for (int n = 0; n < 8; ++n)
            acc[n] = __builtin_amdgcn_mfma_f32_16x16x32_f16(a1, Wf[(1 * 8 + n) * 64 + lane], acc[n], 0, 0, 0);
#pragma unroll
        for (int n = 0; n < 8; ++n)
            acc[n] = __builtin_amdgcn_mfma_f32_16x16x32_f16(a2, Wf[(2 * 8 + n) * 64 + lane], acc[n], 0, 0, 0);
#pragma unroll
        for (int n = 0; n < 8; ++n)
            acc[n] = __builtin_amdgcn_mfma_f32_16x16x32_f16(a3, Wf[(3 * 8 + n) * 64 + lane], acc[n], 0, 0, 0);
#pragma unroll
        for (int n = 0; n < 8; ++n) {
#pragma unroll
            for (int r = 0; r < 4; ++r) {
                int row = r0 + q * 4 + r;
                if (row < NN)
                    hout[(size_t)row * DIM + n * 16 + m] = (_Float16)acc[n][r];
            }
        }
    }
}

// ---------------- fused conv: agg(fp16 gather) + self + bias + L2norm + ReLU (+pool) ----
__launch_bounds__(256, 4)
__global__ void conv_kernel(const half2v* __restrict__ h2, const float* __restrict__ bias,
                            const int* __restrict__ rowp, const vint2* __restrict__ edges,
                            const float* __restrict__ selfn, half2v* __restrict__ out,
                            const int* __restrict__ batch, float* __restrict__ pooled,
                            int do_pool) {
    int wid = threadIdx.x >> 6;
    int lane = threadIdx.x & 63;
    int node = blockIdx.x * 4 + wid;
    if (node >= NN) return;
    int beg = rowp[node], end = rowp[node + 1];
    float ax = 0.f, ay = 0.f;
    int e = beg;
    for (; e + 4 <= end; e += 4) {
        vint2 r0 = __builtin_nontemporal_load(edges + e);
        vint2 r1 = __builtin_nontemporal_load(edges + e + 1);
        vint2 r2 = __builtin_nontemporal_load(edges + e + 2);
        vint2 r3 = __builtin_nontemporal_load(edges + e + 3);
        half2v v0 = h2[(size_t)r0.x * 64 + lane];
        half2v v1 = h2[(size_t)r1.x * 64 + lane];
        half2v v2 = h2[(size_t)r2.x * 64 + lane];
        half2v v3 = h2[(size_t)r3.x * 64 + lane];
        float w0 = __int_as_float(r0.y), w1 = __int_as_float(r1.y);
        float w2 = __int_as_float(r2.y), w3 = __int_as_float(r3.y);
        ax += w0 * (float)v0.x + w1 * (float)v1.x + w2 * (float)v2.x + w3 * (float)v3.x;
        ay += w0 * (float)v0.y + w1 * (float)v1.y + w2 * (float)v2.y + w3 * (float)v3.y;
    }
    for (; e < end; ++e) {
        vint2 r = __builtin_nontemporal_load(edges + e);
        half2v v = h2[(size_t)r.x * 64 + lane];
        float w = __int_as_float(r.y);
        ax += w * (float)v.x;
        ay += w * (float)v.y;
    }
    float sn = selfn[node];
    half2v hv = h2[(size_t)node * 64 + lane];
    ax += sn * (float)hv.x + bias[2 * lane];
    ay += sn * (float)hv.y + bias[2 * lane + 1];
    float ss = ax * ax + ay * ay;
#pragma unroll
    for (int off = 32; off; off >>= 1) ss += __shfl_xor(ss, off);
    float inv = 1.0f / fmaxf(sqrtf(ss), 1e-12f);
    float ox = fmaxf(ax * inv, 0.f);
    float oy = fmaxf(ay * inv, 0.f);
    if (!do_pool) {
        half2v o;
        o.x = (_Float16)ox;
        o.y = (_Float16)oy;
        out[(size_t)node * 64 + lane] = o;   // plain cached store: y stays L2-hot for GEMM
    } else {
        int g = batch[node];
        atomicAdd(&pooled[g * DIM + 2 * lane], ox);
        atomicAdd(&pooled[g * DIM + 2 * lane + 1], oy);
    }
}

// ---------------- head: z = relu(pooled@W1+b1); logits = z@W2+b2 ----------------
__launch_bounds__(128)
__global__ void head_kernel(const float* __restrict__ pooled, const float* __restrict__ w1,
                            const float* __restrict__ b1, const float* __restrict__ w2,
                            const float* __restrict__ b2, float* __restrict__ out) {
    __shared__ float sp[DIM];
    __shared__ float red[4];
    int g = blockIdx.x;
    int k = threadIdx.x;
    sp[k] = pooled[g * DIM + k];
    __syncthreads();
    float acc = b1[k];
#pragma unroll 8
    for (int j = 0; j < DIM; ++j) acc += sp[j] * w1[j * DIM + k];
    float z = fmaxf(acc, 0.f);
    float p0 = z * w2[k * 2 + 0];
    float p1 = z * w2[k * 2 + 1];
#pragma unroll
    for (int off = 32; off; off >>= 1) {
        p0 += __shfl_xor(p0, off);
        p1 += __shfl_xor(p1, off);
    }
    if ((k & 63) == 0) {
        red[(k >> 6) * 2 + 0] = p0;
        red[(k >> 6) * 2 + 1] = p1;
    }
    __syncthreads();
    if (k == 0) {
        out[g * 2 + 0] = red[0] + red[2] + b2[0];
        out[g * 2 + 1] = red[1] + red[3] + b2[1];
    }
}

extern "C" void kernel_launch(void* const* d_in, const int* in_sizes, int n_in,
                              void* d_out, int out_size, void* d_ws, size_t ws_size,
                              hipStream_t stream) {
    const float* x    = (const float*)d_in[0];
    const int* eidx   = (const int*)d_in[1];
    const int* batch  = (const int*)d_in[2];
    const float* W0   = (const float*)d_in[3];
    const float* b0   = (const float*)d_in[4];
    const float* W1   = (const float*)d_in[5];
    const float* b1   = (const float*)d_in[6];
    const float* W2   = (const float*)d_in[7];
    const float* b2   = (const float*)d_in[8];
    const float* l1w  = (const float*)d_in[9];
    const float* l1b  = (const float*)d_in[10];
    const float* l2w  = (const float*)d_in[11];
    const float* l2b  = (const float*)d_in[12];
    float* out = (float*)d_out;

    char* w = (char*)d_ws;
    float* disqrt = (float*)w; w += (size_t)NN * 4;
    float* selfn  = (float*)w; w += (size_t)NN * 4;
    int*   cnt    = (int*)w;   w += (size_t)NN * 4;
    int*   rowp   = (int*)w;   w += (size_t)(NN + 8) * 4;
    int*   cursor = (int*)w;   w += (size_t)NN * 4;
    int*   lexcl  = (int*)w;   w += (size_t)NN * 4;
    int*   bsum   = (int*)w;   w += 256 * 4;
    int*   boffs  = (int*)w;   w += 256 * 4;
    vint2* edges  = (vint2*)w; w += (size_t)NE * 8;
    _Float16* xh  = (_Float16*)w; w += (size_t)NN * DIM * 2;
    _Float16* bufh = (_Float16*)w; w += (size_t)NN * DIM * 2;   // h (GEMM out, gathered)
    _Float16* bufy = (_Float16*)w; w += (size_t)NN * DIM * 2;   // y (conv out)
    float* pooled = (float*)w; w += (size_t)NG * DIM * 4;

    const int* src = eidx;
    const int* dst = eidx + NE;

    init_kernel<<<256, 256, 0, stream>>>(cnt, pooled);
    count_kernel<<<(NE + 255) / 256, 256, 0, stream>>>(dst, cnt);
    scan1_kernel<<<NBLK, 256, 0, stream>>>(cnt, lexcl, bsum, disqrt, selfn);
    scan2_kernel<<<1, 256, 0, stream>>>(bsum, boffs, rowp);
    scan3_kernel<<<NBLK, 256, 0, stream>>>(lexcl, boffs, rowp, cursor);
    scatter_kernel<<<(NE + 255) / 256, 256, 0, stream>>>(src, dst, disqrt, cursor, edges);

    cvt_kernel<<<(NN * DIM / 4 + 255) / 256, 256, 0, stream>>>(x, xh);

    gemm_mfma<<<256, 256, 0, stream>>>(xh, W0, bufh);
    conv_kernel<<<(NN + 3) / 4, 256, 0, stream>>>((const half2v*)bufh, b0, rowp, edges, selfn,
                                                  (half2v*)bufy, batch, pooled, 0);
    gemm_mfma<<<256, 256, 0, stream>>>(bufy, W1, bufh);
    conv_kernel<<<(NN + 3) / 4, 256, 0, stream>>>((const half2v*)bufh, b1, rowp, edges, selfn,
                                                  (half2v*)bufy, batch, pooled, 0);
    gemm_mfma<<<256, 256, 0, stream>>>(bufy, W2, bufh);
    conv_kernel<<<(NN + 3) / 4, 256, 0, stream>>>((const half2v*)bufh, b2, rowp, edges, selfn,
                                                  (half2v*)bufy, batch, pooled, 1);
    head_kernel<<<NG, 128, 0, stream>>>(pooled, l1w, l1b, l2w, l2b, out);
}

// Round 5
// 569.276 us; speedup vs baseline: 1.8475x; 1.0238x over previous
//
#include <hip/hip_runtime.h>

#define NN 50000
#define NE 1600000
#define DIM 128
#define NG  512
#define NT  7            // src tiles of 8192 nodes (50000 >> 13 -> 0..6)
#define TSHIFT 13
#define NK  (NN * NT)    // 350000 sort keys
#define NBLK2 ((NK + 1023) / 1024)   // 342

typedef int      vint2   __attribute__((ext_vector_type(2)));
typedef float    vfloat4 __attribute__((ext_vector_type(4)));
typedef float    floatx4 __attribute__((ext_vector_type(4)));
typedef _Float16 half2v  __attribute__((ext_vector_type(2)));
typedef _Float16 half4v  __attribute__((ext_vector_type(4)));
typedef _Float16 half8   __attribute__((ext_vector_type(8)));

// ---------------- init: zero cnt2 + pooled ----------------
__global__ void init_kernel(int* __restrict__ cnt2, float* __restrict__ pooled) {
    int i = blockIdx.x * blockDim.x + threadIdx.x;
    int stride = gridDim.x * blockDim.x;
    for (int j = i; j < NK; j += stride) cnt2[j] = 0;
    for (int j = i; j < NG * DIM; j += stride) pooled[j] = 0.f;
}

// ---------------- count per (dst, src-tile) key ----------------
__global__ void count2_kernel(const int* __restrict__ src, const int* __restrict__ dst,
                              int* __restrict__ cnt2) {
    int e = blockIdx.x * blockDim.x + threadIdx.x;
    if (e >= NE) return;
    int s = __builtin_nontemporal_load(src + e);
    int d = __builtin_nontemporal_load(dst + e);
    atomicAdd(&cnt2[d * NT + (s >> TSHIFT)], 1);
}

// ---------------- scan phase 1: per-block local scan (1024 keys/block) ----------------
__global__ void scan1_kernel(const int* __restrict__ cnt2, int* __restrict__ lexcl,
                             int* __restrict__ bsum) {
    __shared__ int sd[1024];
    int t = threadIdx.x;
    int i = blockIdx.x * 1024 + t;
    int v = (i < NK) ? cnt2[i] : 0;
    sd[t] = v;
    __syncthreads();
    for (int off = 1; off < 1024; off <<= 1) {
        int add = (t >= off) ? sd[t - off] : 0;
        __syncthreads();
        sd[t] += add;
        __syncthreads();
    }
    int incl = sd[t];
    if (i < NK) lexcl[i] = incl - v;
    if (t == 1023) bsum[blockIdx.x] = incl;
}

// ---------------- scan phase 2: scan block sums (single 1024 block) ----------------
__global__ void scan2_kernel(const int* __restrict__ bsum, int* __restrict__ boffs,
                             int* __restrict__ rowp2) {
    __shared__ int sd[1024];
    int t = threadIdx.x;
    int v = (t < NBLK2) ? bsum[t] : 0;
    sd[t] = v;
    __syncthreads();
    for (int off = 1; off < 1024; off <<= 1) {
        int add = (t >= off) ? sd[t - off] : 0;
        __syncthreads();
        sd[t] += add;
        __syncthreads();
    }
    int incl = sd[t];
    if (t < NBLK2) boffs[t] = incl - v;
    if (t == 1023) rowp2[NK] = incl;   // grand total (== NE)
}

// ---------------- scan phase 3: global offsets ----------------
__global__ void scan3_kernel(const int* __restrict__ lexcl, const int* __restrict__ boffs,
                             int* __restrict__ rowp2, int* __restrict__ cursor2) {
    int i = blockIdx.x * 1024 + threadIdx.x;
    if (i < NK) {
        int v = lexcl[i] + boffs[blockIdx.x];
        rowp2[i] = v;
        cursor2[i] = v;
    }
}

// ---------------- per-node coeffs from rowp2 node boundaries ----------------
__global__ void coeff_kernel(const int* __restrict__ rowp2, float* __restrict__ disqrt,
                             float* __restrict__ selfn) {
    int i = blockIdx.x * blockDim.x + threadIdx.x;
    if (i >= NN) return;
    int deg = rowp2[(i + 1) * NT] - rowp2[i * NT];
    float dg = (float)(deg + 1);
    disqrt[i] = 1.0f / sqrtf(dg);
    selfn[i] = 1.0f / dg;
}

// ---------------- scatter edges into tiled CSR (packed {src, norm}) ----------------
__global__ void scatter_kernel(const int* __restrict__ src, const int* __restrict__ dst,
                               const float* __restrict__ disqrt, int* __restrict__ cursor2,
                               vint2* __restrict__ edges) {
    int e = blockIdx.x * blockDim.x + threadIdx.x;
    if (e >= NE) return;
    int s = __builtin_nontemporal_load(src + e);
    int d = __builtin_nontemporal_load(dst + e);
    float en = disqrt[s] * disqrt[d];
    int pos = atomicAdd(&cursor2[d * NT + (s >> TSHIFT)], 1);
    vint2 rec;
    rec.x = s;
    rec.y = __float_as_int(en);
    __builtin_nontemporal_store(rec, edges + pos);
}

// ---------------- convert x fp32 -> fp16 ----------------
__global__ void cvt_kernel(const float* __restrict__ x, _Float16* __restrict__ xh) {
    int i = blockIdx.x * 256 + threadIdx.x;   // one float4 per thread
    if (i >= NN * DIM / 4) return;
    vfloat4 v = ((const vfloat4*)x)[i];
    half4v o;
    o.x = (_Float16)v.x; o.y = (_Float16)v.y;
    o.z = (_Float16)v.z; o.w = (_Float16)v.w;
    ((half4v*)xh)[i] = o;
}

// ---------------- GEMM via MFMA: h[N,128](fp16) = y[N,128](fp16) @ W[128,128](fp32->fp16) --
__launch_bounds__(256, 2)
__global__ void gemm_mfma(const _Float16* __restrict__ yin, const float* __restrict__ W,
                          _Float16* __restrict__ hout) {
    __shared__ half8 Wf[2048];   // 4 ksteps x 8 ntiles x 64 lanes, 32 KB
    int tid = threadIdx.x;
    for (int idx = tid; idx < 2048; idx += 256) {
        int t = idx >> 9;
        int n = (idx >> 6) & 7;
        int ln = idx & 63;
        int q = ln >> 4, c = ln & 15;
        const float* wp = W + (t * 32 + q * 8) * DIM + n * 16 + c;
        half8 f;
#pragma unroll
        for (int j = 0; j < 8; ++j) f[j] = (_Float16)wp[j * DIM];
        Wf[idx] = f;
    }
    __syncthreads();
    int wid = tid >> 6, lane = tid & 63;
    int q = lane >> 4, m = lane & 15;
    const int ngroups = (NN + 63) / 64;   // 782
    for (int g = blockIdx.x; g < ngroups; g += gridDim.x) {
        int r0 = g * 64 + wid * 16;
        int arow = r0 + m;
        if (arow > NN - 1) arow = NN - 1;      // clamp; corrupt rows never stored
        const half8* ap = (const half8*)(yin + (size_t)arow * DIM + q * 8);
        half8 a0 = ap[0], a1 = ap[4], a2 = ap[8], a3 = ap[12];   // k += 32 per step
        floatx4 acc[8];
#pragma unroll
        for (int n = 0; n < 8; ++n) acc[n] = (floatx4){0.f, 0.f, 0.f, 0.f};
#pragma unroll
        for (int n = 0; n < 8; ++n)
            acc[n] = __builtin_amdgcn_mfma_f32_16x16x32_f16(a0, Wf[(0 * 8 + n) * 64 + lane], acc[n], 0, 0, 0);
#pragma unroll
        for (int n = 0; n < 8; ++n)
            acc[n] = __builtin_amdgcn_mfma_f32_16x16x32_f16(a1, Wf[(1 * 8 + n) * 64 + lane], acc[n], 0, 0, 0);
#pragma unroll
        for (int n = 0; n < 8; ++n)
            acc[n] = __builtin_amdgcn_mfma_f32_16x16x32_f16(a2, Wf[(2 * 8 + n) * 64 + lane], acc[n], 0, 0, 0);
#pragma unroll
        for (int n = 0; n < 8; ++n)
            acc[n] = __builtin_amdgcn_mfma_f32_16x16x32_f16(a3, Wf[(3 * 8 + n) * 64 + lane], acc[n], 0, 0, 0);
#pragma unroll
        for (int n = 0; n < 8; ++n) {
#pragma unroll
            for (int r = 0; r < 4; ++r) {
                int row = r0 + q * 4 + r;
                if (row < NN)
                    hout[(size_t)row * DIM + n * 16 + m] = (_Float16)acc[n][r];
            }
        }
    }
}

// ---------------- fused conv: agg(fp16 gather) + self + bias + L2norm + ReLU (+pool) ----
__launch_bounds__(256, 8)
__global__ void conv_kernel(const half2v* __restrict__ h2, const float* __restrict__ bias,
                            const int* __restrict__ rowp2, const vint2* __restrict__ edges,
                            const float* __restrict__ selfn, half2v* __restrict__ out,
                            const int* __restrict__ batch, float* __restrict__ pooled,
                            int do_pool) {
    int wid = threadIdx.x >> 6;
    int lane = threadIdx.x & 63;
    int node = blockIdx.x * 4 + wid;
    if (node >= NN) return;
    int beg = rowp2[node * NT], end = rowp2[node * NT + NT];
    float ax = 0.f, ay = 0.f;
    int e = beg;
    for (; e + 4 <= end; e += 4) {
        vint2 r0 = __builtin_nontemporal_load(edges + e);
        vint2 r1 = __builtin_nontemporal_load(edges + e + 1);
        vint2 r2 = __builtin_nontemporal_load(edges + e + 2);
        vint2 r3 = __builtin_nontemporal_load(edges + e + 3);
        half2v v0 = h2[(size_t)r0.x * 64 + lane];
        half2v v1 = h2[(size_t)r1.x * 64 + lane];
        half2v v2 = h2[(size_t)r2.x * 64 + lane];
        half2v v3 = h2[(size_t)r3.x * 64 + lane];
        float w0 = __int_as_float(r0.y), w1 = __int_as_float(r1.y);
        float w2 = __int_as_float(r2.y), w3 = __int_as_float(r3.y);
        ax += w0 * (float)v0.x + w1 * (float)v1.x + w2 * (float)v2.x + w3 * (float)v3.x;
        ay += w0 * (float)v0.y + w1 * (float)v1.y + w2 * (float)v2.y + w3 * (float)v3.y;
    }
    for (; e < end; ++e) {
        vint2 r = __builtin_nontemporal_load(edges + e);
        half2v v = h2[(size_t)r.x * 64 + lane];
        float w = __int_as_float(r.y);
        ax += w * (float)v.x;
        ay += w * (float)v.y;
    }
    float sn = selfn[node];
    half2v hv = h2[(size_t)node * 64 + lane];
    ax += sn * (float)hv.x + bias[2 * lane];
    ay += sn * (float)hv.y + bias[2 * lane + 1];
    float ss = ax * ax + ay * ay;
#pragma unroll
    for (int off = 32; off; off >>= 1) ss += __shfl_xor(ss, off);
    float inv = 1.0f / fmaxf(sqrtf(ss), 1e-12f);
    float ox = fmaxf(ax * inv, 0.f);
    float oy = fmaxf(ay * inv, 0.f);
    if (!do_pool) {
        half2v o;
        o.x = (_Float16)ox;
        o.y = (_Float16)oy;
        out[(size_t)node * 64 + lane] = o;   // plain cached store: y stays L2-hot for GEMM
    } else {
        int g = batch[node];
        atomicAdd(&pooled[g * DIM + 2 * lane], ox);
        atomicAdd(&pooled[g * DIM + 2 * lane + 1], oy);
    }
}

// ---------------- head: z = relu(pooled@W1+b1); logits = z@W2+b2 ----------------
__launch_bounds__(128)
__global__ void head_kernel(const float* __restrict__ pooled, const float* __restrict__ w1,
                            const float* __restrict__ b1, const float* __restrict__ w2,
                            const float* __restrict__ b2, float* __restrict__ out) {
    __shared__ float sp[DIM];
    __shared__ float red[4];
    int g = blockIdx.x;
    int k = threadIdx.x;
    sp[k] = pooled[g * DIM + k];
    __syncthreads();
    float acc = b1[k];
#pragma unroll 8
    for (int j = 0; j < DIM; ++j) acc += sp[j] * w1[j * DIM + k];
    float z = fmaxf(acc, 0.f);
    float p0 = z * w2[k * 2 + 0];
    float p1 = z * w2[k * 2 + 1];
#pragma unroll
    for (int off = 32; off; off >>= 1) {
        p0 += __shfl_xor(p0, off);
        p1 += __shfl_xor(p1, off);
    }
    if ((k & 63) == 0) {
        red[(k >> 6) * 2 + 0] = p0;
        red[(k >> 6) * 2 + 1] = p1;
    }
    __syncthreads();
    if (k == 0) {
        out[g * 2 + 0] = red[0] + red[2] + b2[0];
        out[g * 2 + 1] = red[1] + red[3] + b2[1];
    }
}

extern "C" void kernel_launch(void* const* d_in, const int* in_sizes, int n_in,
                              void* d_out, int out_size, void* d_ws, size_t ws_size,
                              hipStream_t stream) {
    const float* x    = (const float*)d_in[0];
    const int* eidx   = (const int*)d_in[1];
    const int* batch  = (const int*)d_in[2];
    const float* W0   = (const float*)d_in[3];
    const float* b0   = (const float*)d_in[4];
    const float* W1   = (const float*)d_in[5];
    const float* b1   = (const float*)d_in[6];
    const float* W2   = (const float*)d_in[7];
    const float* b2   = (const float*)d_in[8];
    const float* l1w  = (const float*)d_in[9];
    const float* l1b  = (const float*)d_in[10];
    const float* l2w  = (const float*)d_in[11];
    const float* l2b  = (const float*)d_in[12];
    float* out = (float*)d_out;

    char* w = (char*)d_ws;
    float* disqrt = (float*)w; w += (size_t)NN * 4;
    float* selfn  = (float*)w; w += (size_t)NN * 4;
    int*   cnt2   = (int*)w;   w += (size_t)NK * 4;
    int*   rowp2  = (int*)w;   w += (size_t)(NK + 8) * 4;
    int*   cursor2= (int*)w;   w += (size_t)NK * 4;
    int*   lexcl  = (int*)w;   w += (size_t)NK * 4;
    int*   bsum   = (int*)w;   w += 1024 * 4;
    int*   boffs  = (int*)w;   w += 1024 * 4;
    vint2* edges  = (vint2*)w; w += (size_t)NE * 8;
    _Float16* xh  = (_Float16*)w; w += (size_t)NN * DIM * 2;
    _Float16* bufh = (_Float16*)w; w += (size_t)NN * DIM * 2;   // h (GEMM out, gathered)
    _Float16* bufy = (_Float16*)w; w += (size_t)NN * DIM * 2;   // y (conv out)
    float* pooled = (float*)w; w += (size_t)NG * DIM * 4;

    const int* src = eidx;
    const int* dst = eidx + NE;

    init_kernel<<<512, 256, 0, stream>>>(cnt2, pooled);
    count2_kernel<<<(NE + 255) / 256, 256, 0, stream>>>(src, dst, cnt2);
    scan1_kernel<<<NBLK2, 1024, 0, stream>>>(cnt2, lexcl, bsum);
    scan2_kernel<<<1, 1024, 0, stream>>>(bsum, boffs, rowp2);
    scan3_kernel<<<NBLK2, 1024, 0, stream>>>(lexcl, boffs, rowp2, cursor2);
    coeff_kernel<<<(NN + 255) / 256, 256, 0, stream>>>(rowp2, disqrt, selfn);
    scatter_kernel<<<(NE + 255) / 256, 256, 0, stream>>>(src, dst, disqrt, cursor2, edges);

    cvt_kernel<<<(NN * DIM / 4 + 255) / 256, 256, 0, stream>>>(x, xh);

    gemm_mfma<<<256, 256, 0, stream>>>(xh, W0, bufh);
    conv_kernel<<<(NN + 3) / 4, 256, 0, stream>>>((const half2v*)bufh, b0, rowp2, edges, selfn,
                                                  (half2v*)bufy, batch, pooled, 0);
    gemm_mfma<<<256, 256, 0, stream>>>(bufy, W1, bufh);
    conv_kernel<<<(NN + 3) / 4, 256, 0, stream>>>((const half2v*)bufh, b1, rowp2, edges, selfn,
                                                  (half2v*)bufy, batch, pooled, 0);
    gemm_mfma<<<256, 256, 0, stream>>>(bufy, W2, bufh);
    conv_kernel<<<(NN + 3) / 4, 256, 0, stream>>>((const half2v*)bufh, b2, rowp2, edges, selfn,
                                                  (half2v*)bufy, batch, pooled, 1);
    head_kernel<<<NG, 128, 0, stream>>>(pooled, l1w, l1b, l2w, l2b, out);
}